// Round 7
// baseline (405.467 us; speedup 1.0000x reference)
//
#include <hip/hip_runtime.h>
#include <hip/hip_bf16.h>
#include <cstdint>
#include <cstddef>

#define S_LEN 2048
#define HID_DIM 4096
#define NH 32
#define NKV 8
#define HD 128
#define LOG2E 1.4426950408889634f
#define SCALE 0.08838834764831845f

typedef __attribute__((ext_vector_type(8))) short bf16x8;
typedef __attribute__((ext_vector_type(4))) float f32x4;
typedef __attribute__((ext_vector_type(16))) float f32x16;
typedef __attribute__((ext_vector_type(4))) short short4v;
typedef __attribute__((ext_vector_type(4))) unsigned u32x4;

__device__ __forceinline__ short f2bf(float f) {
  union { float f; unsigned u; } v; v.f = f;
  return (short)((v.u + 0x7fffu + ((v.u >> 16) & 1u)) >> 16);
}
__device__ __forceinline__ float bf2f(short s) {
  union { unsigned u; float f; } v; v.u = ((unsigned)(unsigned short)s) << 16;
  return v.f;
}
__device__ __forceinline__ unsigned cvt_pk_bf16(float lo, float hi) {
  unsigned r;
  asm("v_cvt_pk_bf16_f32 %0, %1, %2" : "=v"(r) : "v"(lo), "v"(hi));
  return r;
}
__device__ __forceinline__ void gld_lds16(const void* g, void* l) {
  __builtin_amdgcn_global_load_lds((const __attribute__((address_space(1))) unsigned*)g,
                                   (__attribute__((address_space(3))) unsigned*)l, 16, 0, 0);
}

#define WAITVM8() asm volatile("s_waitcnt vmcnt(8)" ::: "memory")
#define WAITVM4() asm volatile("s_waitcnt vmcnt(4)" ::: "memory")
#define WAITVM0() asm volatile("s_waitcnt vmcnt(0)" ::: "memory")

// ---------------- fp32 -> bf16 elementwise ----------------
__global__ void cvt_kernel(const float* __restrict__ in, short* __restrict__ out, int n) {
  int i = (blockIdx.x * 256 + threadIdx.x) * 4;
  if (i < n) {
    float4 f = *(const float4*)(in + i);
    short4v o = { f2bf(f.x), f2bf(f.y), f2bf(f.z), f2bf(f.w) };
    *(short4v*)(out + i) = o;
  }
}

// ---------------- fp32 [R][C] -> bf16 [C][R] transpose-convert ----------------
__global__ void tconv_kernel(const float* __restrict__ in, short* __restrict__ out, int R, int C) {
  __shared__ float tile[32][33];
  int tr = blockIdx.y * 32, tc = blockIdx.x * 32;
  int tx = threadIdx.x & 31, ty = threadIdx.x >> 5; // ty 0..7
#pragma unroll
  for (int i = 0; i < 32; i += 8)
    tile[ty + i][tx] = in[(size_t)(tr + ty + i) * C + tc + tx];
  __syncthreads();
#pragma unroll
  for (int i = 0; i < 32; i += 8)
    out[(size_t)(tc + ty + i) * R + tr + tx] = f2bf(tile[tx][ty + i]);
}

// ---------------- GEMM: C[M][N] = A[M][K] * Bt[N][K]^T ----------------
// Double-buffered LDS, counted vmcnt, 4 blocks/CU, per-XCD squarish regions.
// MODE 2: write fp32 out[m][n]
// MODE 3: fused QKV epilogue.
template<int MODE>
__global__ __launch_bounds__(256, 4) void gemm_bt_kernel(
    const short* __restrict__ A, const short* __restrict__ Bt,
    void* __restrict__ Cout, int M, int N, int K, int rchunk, int cchunk)
{
  __shared__ short As[2][128 * 32];
  __shared__ short Bs[2][128 * 32];
  const int tid = threadIdx.x;
  const int lane = tid & 63;
  const int w = tid >> 6;
  const int wm = w >> 1, wn = w & 1;
  const int xcd = blockIdx.x & 7;
  const int local = blockIdx.x >> 3;
  const int by = (xcd >> 2) * rchunk + (local % rchunk);
  const int bx = (xcd & 3) * cchunk + (local / rchunk);
  const int m0 = by * 128, n0 = bx * 128;

  auto stage = [&](int bb, int k0) {
#pragma unroll
    for (int rep = 0; rep < 2; rep++) {
      int c = rep * 256 + tid;
      int row = c >> 2, slot = c & 3;
      int gs = slot ^ (row & 3);
      gld_lds16(A + (size_t)(m0 + row) * K + k0 + gs * 8, &As[bb][c * 8]);
      gld_lds16(Bt + (size_t)(n0 + row) * K + k0 + gs * 8, &Bs[bb][c * 8]);
    }
  };

  f32x4 acc[4][4];
#pragma unroll
  for (int i = 0; i < 4; i++)
#pragma unroll
    for (int j = 0; j < 4; j++) acc[i][j] = (f32x4){0.f, 0.f, 0.f, 0.f};

  const int NT = K >> 5;
  stage(0, 0);
  for (int kt = 0; kt < NT; kt++) {
    const int b = kt & 1;
    if (kt + 1 < NT) { stage(b ^ 1, (kt + 1) << 5); WAITVM4(); }
    else             { WAITVM0(); }
    __builtin_amdgcn_s_barrier();

    bf16x8 af[4], bf[4];
#pragma unroll
    for (int ms = 0; ms < 4; ms++) {
      int row = wm * 64 + ms * 16 + (lane & 15);
      af[ms] = *(const bf16x8*)(&As[b][row * 32 + (((lane >> 4) ^ (row & 3)) << 3)]);
    }
#pragma unroll
    for (int ns = 0; ns < 4; ns++) {
      int row = wn * 64 + ns * 16 + (lane & 15);
      bf[ns] = *(const bf16x8*)(&Bs[b][row * 32 + (((lane >> 4) ^ (row & 3)) << 3)]);
    }
#pragma unroll
    for (int ms = 0; ms < 4; ms++)
#pragma unroll
      for (int ns = 0; ns < 4; ns++)
        acc[ms][ns] = __builtin_amdgcn_mfma_f32_16x16x32_bf16(af[ms], bf[ns], acc[ms][ns], 0, 0, 0);

    __builtin_amdgcn_s_barrier();
  }

#pragma unroll
  for (int ms = 0; ms < 4; ms++) {
    int mb = m0 + wm * 64 + ms * 16 + ((lane >> 4) << 2);
#pragma unroll
    for (int ns = 0; ns < 4; ns++) {
      int n = n0 + wn * 64 + ns * 16 + (lane & 15);
      if (MODE == 3) {
        short* o = (short*)Cout;
        if (n < NH * HD) {
          int head = n >> 7, d = n & 127;
#pragma unroll
          for (int r = 0; r < 4; r++)
            o[((size_t)head * M + (mb + r)) * HD + d] = f2bf(acc[ms][ns][r]);
        } else if (n < (NH + NKV) * HD) {
          int head = (n - NH * HD) >> 7, d = n & 127;
          short* ok = o + (size_t)NH * S_LEN * HD;
#pragma unroll
          for (int r = 0; r < 4; r++)
            ok[((size_t)head * M + (mb + r)) * HD + d] = f2bf(acc[ms][ns][r]);
        } else {
          int head = (n - (NH + NKV) * HD) >> 7, d = n & 127;
          short* ov = o + (size_t)(NH + NKV) * S_LEN * HD;
          short4v pk;
#pragma unroll
          for (int r = 0; r < 4; r++) pk[r] = f2bf(acc[ms][ns][r]);
          *(short4v*)(ov + ((size_t)head * HD + d) * M + mb) = pk;
        }
      } else {
        float* o = (float*)Cout;
#pragma unroll
        for (int r = 0; r < 4; r++)
          o[(size_t)(mb + r) * N + n] = acc[ms][ns][r];
      }
    }
  }
}

// ---------------- RoPE in-place on Q [NH][S][HD] and K [NKV][S][HD] (bf16) ----------------
__global__ void rope_kernel(short* __restrict__ q, short* __restrict__ k,
                            const int* __restrict__ pos_ids) {
  const int s = blockIdx.x;
  const int hh = blockIdx.y * 4 + threadIdx.y;  // 0..39
  const int d = threadIdx.x;                    // 0..63
  const float pos = (float)pos_ids[s];
  const float inv = __expf(-(float)d * 0.14391157f); // ln(10000)/64
  float sn, c;
  __sincosf(pos * inv, &sn, &c);
  short* base = (hh < NH) ? (q + ((size_t)hh * S_LEN + s) * HD)
                          : (k + ((size_t)(hh - NH) * S_LEN + s) * HD);
  float x1 = bf2f(base[d]), x2 = bf2f(base[d + 64]);
  base[d] = f2bf(x1 * c - x2 * sn);
  base[d + 64] = f2bf(x2 * c + x1 * sn);
}

// ---------------- flash attention + eviction scores (32x32x16 MFMA) ----------------
// 256 blocks x 256 threads (4 waves x 32 q-rows = 128 rows/strip). Block ->
// (head, pair p): strips qt=p and 15-p sequentially -> uniform work. kvh==XCD.
// K stored in LDS with key bits 2<->3 swapped: swapped QK^T (C[key][q]) output
// is then exactly lane-local for the PV A-fragment: pa[s] = sf[s>>1] regs
// [8*(s&1)..+8). Double-buffered staging with counted vmcnt. Fixed softmax
// basis m==0; per-thread l partial, one reduce per strip.
__global__ __launch_bounds__(256, 2) void attn_kernel(
    const short* __restrict__ Qr, const short* __restrict__ Kr, const short* __restrict__ Vt,
    short* __restrict__ attn_out, float* __restrict__ scores)
{
  __shared__ short Ks[2][64 * 128];  // [permrow][hd], 16B slots XOR-swizzled by (row&7)
  __shared__ short Vs[2][128 * 64];  // [d][key],     16B slots XOR-swizzled by (d&7)
  __shared__ float cs[2048];

  const int tid = threadIdx.x;
  const int lane = tid & 63;
  const int w = tid >> 6;        // 0..3
  const int h2 = lane >> 5;      // k-half
  const int l31 = lane & 31;
  const int lin = (blockIdx.x & 7) * 32 + (blockIdx.x >> 3);
  const int h = lin >> 3;        // 0..31
  const int pr = lin & 7;        // pair 0..7
  const int kvh = h >> 2;
  const float CS = SCALE * LOG2E;

  const short* KrB = Kr + (size_t)kvh * S_LEN * HD;
  const short* VtB = Vt + (size_t)kvh * HD * S_LEN;

  for (int i = tid; i < 2048; i += 256) cs[i] = 0.f;

  auto stageK = [&](int bb, int t) {
    const int kb2 = t * 64;
#pragma unroll
    for (int rep = 0; rep < 4; rep++) {
      int c = rep * 256 + tid;
      int x = c >> 4, slot = c & 15;
      int key = (x & 0x33) | ((x & 4) << 1) | ((x & 8) >> 1);  // swap bits 2,3
      int gs = slot ^ (x & 7);
      gld_lds16(KrB + (size_t)(kb2 + key) * HD + gs * 8, &Ks[bb][c * 8]);
    }
  };
  auto stageV = [&](int bb, int t) {
    const int kb2 = t * 64;
#pragma unroll
    for (int rep = 0; rep < 4; rep++) {
      int c = rep * 256 + tid;
      int d = c >> 3, slot = c & 7;
      int gs = slot ^ (d & 7);
      gld_lds16(VtB + (size_t)d * S_LEN + kb2 + gs * 8, &Vs[bb][c * 8]);
    }
  };

  const int maxnt = 2 * (15 - pr) + 2;

  for (int sidx = 0; sidx < 2; sidx++) {
    const int qt = sidx ? (15 - pr) : pr;
    const int nt = 2 * qt + 2;
    const int qbase = qt * 128 + w * 32;
    const int qglob = qbase + l31;
    const int qmaxw = qbase + 31;

    // Q fragments: q = qglob, hd = kc*16 + h2*8 + j
    bf16x8 qf[8];
    {
      const short* qrow = Qr + ((size_t)h * S_LEN + qglob) * HD + h2 * 8;
#pragma unroll
      for (int kc = 0; kc < 8; kc++) qf[kc] = *(const bf16x8*)(qrow + kc * 16);
    }

    f32x16 oacc[4];
#pragma unroll
    for (int i = 0; i < 4; i++) oacc[i] = (f32x16)(0.f);
    float lsum = 0.f;

    // ---------- phase 1 ----------
    stageK(0, 0); stageV(0, 0);
    for (int t = 0; t < nt; t++) {
      const int b = t & 1;
      const int kb = t * 64;
      if (t + 1 < nt) { stageK(b ^ 1, t + 1); stageV(b ^ 1, t + 1); WAITVM8(); }
      else            { WAITVM0(); }
      __builtin_amdgcn_s_barrier();

      if (kb <= qmaxw) {
        // QK^T swapped: C[permkey][q]
        f32x16 sf[2];
        sf[0] = (f32x16)(0.f); sf[1] = (f32x16)(0.f);
        __builtin_amdgcn_s_setprio(1);
#pragma unroll
        for (int kc = 0; kc < 8; kc++)
#pragma unroll
          for (int bl = 0; bl < 2; bl++) {
            int x = bl * 32 + l31;
            bf16x8 kf = *(const bf16x8*)(&Ks[b][x * 128 + (((kc * 2 + h2) ^ (lane & 7)) << 3)]);
            sf[bl] = __builtin_amdgcn_mfma_f32_32x32x16_bf16(kf, qf[kc], sf[bl], 0, 0, 0);
          }
        __builtin_amdgcn_s_setprio(0);

        // softmax (fixed basis 0); real key of sf[bl][4a+c] =
        // kb + bl*32 + (a>>1)*16 + h2*8 + (a&1)*4 + c
        float p[2][16];
        const bool diag = (kb + 63 > qbase);
#pragma unroll
        for (int bl = 0; bl < 2; bl++)
#pragma unroll
          for (int a = 0; a < 4; a++)
#pragma unroll
            for (int cc = 0; cc < 4; cc++) {
              float pv = exp2f(sf[bl][a * 4 + cc] * CS);
              if (diag) {
                int key = kb + bl * 32 + (a >> 1) * 16 + h2 * 8 + (a & 1) * 4 + cc;
                if (key > qglob) pv = 0.f;
              }
              p[bl][a * 4 + cc] = pv;
              lsum += pv;
            }

        // pack PV A-frags: pa[s] elem j = p[s>>1][8*(s&1) + j]
        bf16x8 pa[4];
#pragma unroll
        for (int s = 0; s < 4; s++) {
          const int bl = s >> 1, base = 8 * (s & 1);
          u32x4 pw;
          pw[0] = cvt_pk_bf16(p[bl][base + 0], p[bl][base + 1]);
          pw[1] = cvt_pk_bf16(p[bl][base + 2], p[bl][base + 3]);
          pw[2] = cvt_pk_bf16(p[bl][base + 4], p[bl][base + 5]);
          pw[3] = cvt_pk_bf16(p[bl][base + 6], p[bl][base + 7]);
          pa[s] = __builtin_bit_cast(bf16x8, pw);
        }

        // PV: C[q][d]
        __builtin_amdgcn_s_setprio(1);
#pragma unroll
        for (int s = 0; s < 4; s++)
#pragma unroll
          for (int db = 0; db < 4; db++) {
            int d = db * 32 + l31;
            bf16x8 vf = *(const bf16x8*)(&Vs[b][d * 64 + (((s * 2 + h2) ^ (lane & 7)) << 3)]);
            oacc[db] = __builtin_amdgcn_mfma_f32_32x32x16_bf16(pa[s], vf, oacc[db], 0, 0, 0);
          }
        __builtin_amdgcn_s_setprio(0);
      }
      __builtin_amdgcn_s_barrier();
    }

    // l reduce (halves) -> per-reg reciprocal table
    lsum += __shfl_xor(lsum, 32);
    float rlv = 1.f / lsum;           // valid for q-row = l31
    float rl16[16];
#pragma unroll
    for (int r = 0; r < 16; r++)
      rl16[r] = __shfl(rlv, (r & 3) + 8 * (r >> 2) + 4 * h2);

    // write O: lane holds d-col = db*32 + l31, q-rows by reg
#pragma unroll
    for (int db = 0; db < 4; db++) {
      int d = db * 32 + l31;
#pragma unroll
      for (int r = 0; r < 16; r++) {
        int qq = qbase + (r & 3) + 8 * (r >> 2) + 4 * h2;
        attn_out[(size_t)qq * HID_DIM + h * HD + d] = f2bf(oacc[db][r] * rl16[r]);
      }
    }

    // ---------- phase 2: normalized prob column sums ----------
    const int xl = (l31 & 0x13) | ((l31 & 4) << 1) | ((l31 & 8) >> 1);  // perm5
    stageK(0, 0);
    for (int t = 0; t < nt; t++) {
      const int b = t & 1;
      const int kb = t * 64;
      if (t + 1 < nt) { stageK(b ^ 1, t + 1); WAITVM4(); }
      else            { WAITVM0(); }
      __builtin_amdgcn_s_barrier();

      if (kb <= qmaxw) {
        // unswapped: C[q][key], key-col = bl*32 + l31 via LDS row bl*32 + xl
        f32x16 sg[2];
        sg[0] = (f32x16)(0.f); sg[1] = (f32x16)(0.f);
        __builtin_amdgcn_s_setprio(1);
#pragma unroll
        for (int kc = 0; kc < 8; kc++)
#pragma unroll
          for (int bl = 0; bl < 2; bl++) {
            int x = bl * 32 + xl;
            bf16x8 kf = *(const bf16x8*)(&Ks[b][x * 128 + (((kc * 2 + h2) ^ (x & 7)) << 3)]);
            sg[bl] = __builtin_amdgcn_mfma_f32_32x32x16_bf16(qf[kc], kf, sg[bl], 0, 0, 0);
          }
        __builtin_amdgcn_s_setprio(0);

        const bool diag = (kb + 63 > qbase);
#pragma unroll
        for (int bl = 0; bl < 2; bl++) {
          int key = kb + bl * 32 + l31;
          float sum = 0.f;
#pragma unroll
          for (int r = 0; r < 16; r++) {
            float pv = exp2f(sg[bl][r] * CS) * rl16[r];
            if (diag && key > qbase + (r & 3) + 8 * (r >> 2) + 4 * h2) pv = 0.f;
            sum += pv;
          }
          sum += __shfl_xor(sum, 32);
          if (lane < 32) atomicAdd(&cs[key], sum);
        }
      }
      __builtin_amdgcn_s_barrier();
    }
  }

  // flush colsums
  asm volatile("s_waitcnt lgkmcnt(0)" ::: "memory");
  __builtin_amdgcn_s_barrier();
  const int nk = maxnt * 64;
  for (int i = tid; i < nk; i += 256)
    atomicAdd(scores + (size_t)kvh * S_LEN + i, cs[i]);
}

// ---------------- launch ----------------
extern "C" void kernel_launch(void* const* d_in, const int* in_sizes, int n_in,
                              void* d_out, int out_size, void* d_ws, size_t ws_size,
                              hipStream_t stream) {
  const float* hs = (const float*)d_in[0];
  const float* wq = (const float*)d_in[1];
  const float* wk = (const float*)d_in[2];
  const float* wv = (const float*)d_in[3];
  const float* wo = (const float*)d_in[4];
  const int* pos = (const int*)d_in[5];
  float* out = (float*)d_out;

  char* ws = (char*)d_ws;
  const size_t off_hs   = 0;
  const size_t off_wqT  = off_hs   + (size_t)S_LEN * HID_DIM * 2;
  const size_t off_wkT  = off_wqT  + (size_t)HID_DIM * HID_DIM * 2;
  const size_t off_wvT  = off_wkT  + (size_t)1024 * HID_DIM * 2;
  const size_t off_woT  = off_wvT  + (size_t)1024 * HID_DIM * 2;
  const size_t off_Qr   = off_woT  + (size_t)HID_DIM * HID_DIM * 2;
  const size_t off_Kr   = off_Qr   + (size_t)NH * S_LEN * HD * 2;
  const size_t off_Vt   = off_Kr   + (size_t)NKV * S_LEN * HD * 2;
  const size_t off_attn = off_Vt   + (size_t)NKV * HD * S_LEN * 2;

  short* hsb  = (short*)(ws + off_hs);
  short* wqT  = (short*)(ws + off_wqT);
  short* wkT  = (short*)(ws + off_wkT);
  short* wvT  = (short*)(ws + off_wvT);
  short* woT  = (short*)(ws + off_woT);
  short* Qr   = (short*)(ws + off_Qr);
  short* Kr   = (short*)(ws + off_Kr);
  short* Vt   = (short*)(ws + off_Vt);
  short* attb = (short*)(ws + off_attn);

  cvt_kernel<<<dim3((S_LEN * HID_DIM) / 1024), 256, 0, stream>>>(hs, hsb, S_LEN * HID_DIM);
  tconv_kernel<<<dim3(128, 128), 256, 0, stream>>>(wq, wqT, HID_DIM, HID_DIM);
  tconv_kernel<<<dim3(32, 128), 256, 0, stream>>>(wk, wkT, HID_DIM, 1024);
  tconv_kernel<<<dim3(32, 128), 256, 0, stream>>>(wv, wvT, HID_DIM, 1024);
  tconv_kernel<<<dim3(128, 128), 256, 0, stream>>>(wo, woT, HID_DIM, HID_DIM);

  gemm_bt_kernel<3><<<768, 256, 0, stream>>>(hsb, wqT, Qr, S_LEN, 6144, HID_DIM, 8, 12);

  rope_kernel<<<dim3(S_LEN, 10), dim3(64, 4), 0, stream>>>(Qr, Kr, pos);

  hipMemsetAsync(out + (size_t)S_LEN * HID_DIM, 0, (size_t)NKV * S_LEN * sizeof(float), stream);
  attn_kernel<<<256, 256, 0, stream>>>(Qr, Kr, Vt, attb, out + (size_t)S_LEN * HID_DIM);

  gemm_bt_kernel<2><<<512, 256, 0, stream>>>(attb, woT, out, S_LEN, HID_DIM, HID_DIM, 8, 8);
}

// Round 8
// 401.677 us; speedup vs baseline: 1.0094x; 1.0094x over previous
//
#include <hip/hip_runtime.h>
#include <hip/hip_bf16.h>
#include <cstdint>
#include <cstddef>

#define S_LEN 2048
#define HID_DIM 4096
#define NH 32
#define NKV 8
#define HD 128
#define LOG2E 1.4426950408889634f
#define SCALE 0.08838834764831845f

typedef __attribute__((ext_vector_type(8))) short bf16x8;
typedef __attribute__((ext_vector_type(4))) float f32x4;
typedef __attribute__((ext_vector_type(16))) float f32x16;
typedef __attribute__((ext_vector_type(4))) short short4v;
typedef __attribute__((ext_vector_type(4))) unsigned u32x4;

__device__ __forceinline__ short f2bf(float f) {
  union { float f; unsigned u; } v; v.f = f;
  return (short)((v.u + 0x7fffu + ((v.u >> 16) & 1u)) >> 16);
}
__device__ __forceinline__ float bf2f(short s) {
  union { unsigned u; float f; } v; v.u = ((unsigned)(unsigned short)s) << 16;
  return v.f;
}
__device__ __forceinline__ unsigned cvt_pk_bf16(float lo, float hi) {
  unsigned r;
  asm("v_cvt_pk_bf16_f32 %0, %1, %2" : "=v"(r) : "v"(lo), "v"(hi));
  return r;
}
__device__ __forceinline__ void gld_lds16(const void* g, void* l) {
  __builtin_amdgcn_global_load_lds((const __attribute__((address_space(1))) unsigned*)g,
                                   (__attribute__((address_space(3))) unsigned*)l, 16, 0, 0);
}

#define WAITVM8() asm volatile("s_waitcnt vmcnt(8)" ::: "memory")
#define WAITVM4() asm volatile("s_waitcnt vmcnt(4)" ::: "memory")
#define WAITVM0() asm volatile("s_waitcnt vmcnt(0)" ::: "memory")

// ---------------- fp32 -> bf16 elementwise ----------------
__global__ void cvt_kernel(const float* __restrict__ in, short* __restrict__ out, int n) {
  int i = (blockIdx.x * 256 + threadIdx.x) * 4;
  if (i < n) {
    float4 f = *(const float4*)(in + i);
    short4v o = { f2bf(f.x), f2bf(f.y), f2bf(f.z), f2bf(f.w) };
    *(short4v*)(out + i) = o;
  }
}

// ---------------- fp32 [R][C] -> bf16 [C][R] transpose-convert ----------------
__global__ void tconv_kernel(const float* __restrict__ in, short* __restrict__ out, int R, int C) {
  __shared__ float tile[32][33];
  int tr = blockIdx.y * 32, tc = blockIdx.x * 32;
  int tx = threadIdx.x & 31, ty = threadIdx.x >> 5; // ty 0..7
#pragma unroll
  for (int i = 0; i < 32; i += 8)
    tile[ty + i][tx] = in[(size_t)(tr + ty + i) * C + tc + tx];
  __syncthreads();
#pragma unroll
  for (int i = 0; i < 32; i += 8)
    out[(size_t)(tc + ty + i) * R + tr + tx] = f2bf(tile[tx][ty + i]);
}

// ---------------- GEMM: C[M][N] = A[M][K] * Bt[N][K]^T ----------------
// Double-buffered LDS, counted vmcnt, 4 blocks/CU, per-XCD squarish regions.
// MODE 2: write fp32 out[m][n]
// MODE 3: fused QKV epilogue.
template<int MODE>
__global__ __launch_bounds__(256, 4) void gemm_bt_kernel(
    const short* __restrict__ A, const short* __restrict__ Bt,
    void* __restrict__ Cout, int M, int N, int K, int rchunk, int cchunk)
{
  __shared__ short As[2][128 * 32];
  __shared__ short Bs[2][128 * 32];
  const int tid = threadIdx.x;
  const int lane = tid & 63;
  const int w = tid >> 6;
  const int wm = w >> 1, wn = w & 1;
  const int xcd = blockIdx.x & 7;
  const int local = blockIdx.x >> 3;
  const int by = (xcd >> 2) * rchunk + (local % rchunk);
  const int bx = (xcd & 3) * cchunk + (local / rchunk);
  const int m0 = by * 128, n0 = bx * 128;

  auto stage = [&](int bb, int k0) {
#pragma unroll
    for (int rep = 0; rep < 2; rep++) {
      int c = rep * 256 + tid;
      int row = c >> 2, slot = c & 3;
      int gs = slot ^ (row & 3);
      gld_lds16(A + (size_t)(m0 + row) * K + k0 + gs * 8, &As[bb][c * 8]);
      gld_lds16(Bt + (size_t)(n0 + row) * K + k0 + gs * 8, &Bs[bb][c * 8]);
    }
  };

  f32x4 acc[4][4];
#pragma unroll
  for (int i = 0; i < 4; i++)
#pragma unroll
    for (int j = 0; j < 4; j++) acc[i][j] = (f32x4){0.f, 0.f, 0.f, 0.f};

  const int NT = K >> 5;
  stage(0, 0);
  for (int kt = 0; kt < NT; kt++) {
    const int b = kt & 1;
    if (kt + 1 < NT) { stage(b ^ 1, (kt + 1) << 5); WAITVM4(); }
    else             { WAITVM0(); }
    __builtin_amdgcn_s_barrier();

    bf16x8 af[4], bf[4];
#pragma unroll
    for (int ms = 0; ms < 4; ms++) {
      int row = wm * 64 + ms * 16 + (lane & 15);
      af[ms] = *(const bf16x8*)(&As[b][row * 32 + (((lane >> 4) ^ (row & 3)) << 3)]);
    }
#pragma unroll
    for (int ns = 0; ns < 4; ns++) {
      int row = wn * 64 + ns * 16 + (lane & 15);
      bf[ns] = *(const bf16x8*)(&Bs[b][row * 32 + (((lane >> 4) ^ (row & 3)) << 3)]);
    }
#pragma unroll
    for (int ms = 0; ms < 4; ms++)
#pragma unroll
      for (int ns = 0; ns < 4; ns++)
        acc[ms][ns] = __builtin_amdgcn_mfma_f32_16x16x32_bf16(af[ms], bf[ns], acc[ms][ns], 0, 0, 0);

    __builtin_amdgcn_s_barrier();
  }

#pragma unroll
  for (int ms = 0; ms < 4; ms++) {
    int mb = m0 + wm * 64 + ms * 16 + ((lane >> 4) << 2);
#pragma unroll
    for (int ns = 0; ns < 4; ns++) {
      int n = n0 + wn * 64 + ns * 16 + (lane & 15);
      if (MODE == 3) {
        short* o = (short*)Cout;
        if (n < NH * HD) {
          int head = n >> 7, d = n & 127;
#pragma unroll
          for (int r = 0; r < 4; r++)
            o[((size_t)head * M + (mb + r)) * HD + d] = f2bf(acc[ms][ns][r]);
        } else if (n < (NH + NKV) * HD) {
          int head = (n - NH * HD) >> 7, d = n & 127;
          short* ok = o + (size_t)NH * S_LEN * HD;
#pragma unroll
          for (int r = 0; r < 4; r++)
            ok[((size_t)head * M + (mb + r)) * HD + d] = f2bf(acc[ms][ns][r]);
        } else {
          int head = (n - (NH + NKV) * HD) >> 7, d = n & 127;
          short* ov = o + (size_t)(NH + NKV) * S_LEN * HD;
          short4v pk;
#pragma unroll
          for (int r = 0; r < 4; r++) pk[r] = f2bf(acc[ms][ns][r]);
          *(short4v*)(ov + ((size_t)head * HD + d) * M + mb) = pk;
        }
      } else {
        float* o = (float*)Cout;
#pragma unroll
        for (int r = 0; r < 4; r++)
          o[(size_t)(mb + r) * N + n] = acc[ms][ns][r];
      }
    }
  }
}

// ---------------- RoPE in-place on Q [NH][S][HD] and K [NKV][S][HD] (bf16) ----------------
__global__ void rope_kernel(short* __restrict__ q, short* __restrict__ k,
                            const int* __restrict__ pos_ids) {
  const int s = blockIdx.x;
  const int hh = blockIdx.y * 4 + threadIdx.y;  // 0..39
  const int d = threadIdx.x;                    // 0..63
  const float pos = (float)pos_ids[s];
  const float inv = __expf(-(float)d * 0.14391157f); // ln(10000)/64
  float sn, c;
  __sincosf(pos * inv, &sn, &c);
  short* base = (hh < NH) ? (q + ((size_t)hh * S_LEN + s) * HD)
                          : (k + ((size_t)(hh - NH) * S_LEN + s) * HD);
  float x1 = bf2f(base[d]), x2 = bf2f(base[d + 64]);
  base[d] = f2bf(x1 * c - x2 * sn);
  base[d + 64] = f2bf(x2 * c + x1 * sn);
}

// ---------------- flash attention + eviction scores (32x32x16 MFMA) ----------------
// 512 blocks x 256 threads (4 waves x 32 q-rows = 128-row strip each).
// Block -> (head, strip): per XCD, j<32 gets heavy strip qt=15-(j>>2),
// j>=32 gets light strip qt=(j-32)>>2 -> the 2 co-resident blocks/CU pair
// heavy+light (sum ~17 tile-units). kvh == XCD for K/V L2 locality.
// K stored in LDS with key bits 2<->3 swapped: swapped QK^T (C[key][q]) output
// is exactly lane-local for the PV A-fragment. Double-buffered staging with
// counted vmcnt. Fixed softmax basis m==0; per-thread l partial, one reduce.
__global__ __launch_bounds__(256, 2) void attn_kernel(
    const short* __restrict__ Qr, const short* __restrict__ Kr, const short* __restrict__ Vt,
    short* __restrict__ attn_out, float* __restrict__ scores)
{
  __shared__ short Ks[2][64 * 128];  // [permrow][hd], 16B slots XOR-swizzled by (row&7)
  __shared__ short Vs[2][128 * 64];  // [d][key],     16B slots XOR-swizzled by (d&7)
  __shared__ float cs[2048];

  const int tid = threadIdx.x;
  const int lane = tid & 63;
  const int w = tid >> 6;        // 0..3
  const int h2 = lane >> 5;      // k-half
  const int l31 = lane & 31;
  const int xcd = blockIdx.x & 7;
  const int j = blockIdx.x >> 3; // 0..63
  const int qt = (j < 32) ? (15 - (j >> 2)) : ((j - 32) >> 2);
  const int h = xcd * 4 + (j & 3);
  const int kvh = xcd;
  const float CS = SCALE * LOG2E;

  const short* KrB = Kr + (size_t)kvh * S_LEN * HD;
  const short* VtB = Vt + (size_t)kvh * HD * S_LEN;

  for (int i = tid; i < 2048; i += 256) cs[i] = 0.f;

  auto stageK = [&](int bb, int t) {
    const int kb2 = t * 64;
#pragma unroll
    for (int rep = 0; rep < 4; rep++) {
      int c = rep * 256 + tid;
      int x = c >> 4, slot = c & 15;
      int key = (x & 0x33) | ((x & 4) << 1) | ((x & 8) >> 1);  // swap bits 2,3
      int gs = slot ^ (x & 7);
      gld_lds16(KrB + (size_t)(kb2 + key) * HD + gs * 8, &Ks[bb][c * 8]);
    }
  };
  auto stageV = [&](int bb, int t) {
    const int kb2 = t * 64;
#pragma unroll
    for (int rep = 0; rep < 4; rep++) {
      int c = rep * 256 + tid;
      int d = c >> 3, slot = c & 7;
      int gs = slot ^ (d & 7);
      gld_lds16(VtB + (size_t)d * S_LEN + kb2 + gs * 8, &Vs[bb][c * 8]);
    }
  };

  const int nt = 2 * qt + 2;
  const int qbase = qt * 128 + w * 32;
  const int qglob = qbase + l31;
  const int qmaxw = qbase + 31;

  // Q fragments: q = qglob, hd = kc*16 + h2*8 + j
  bf16x8 qf[8];
  {
    const short* qrow = Qr + ((size_t)h * S_LEN + qglob) * HD + h2 * 8;
#pragma unroll
    for (int kc = 0; kc < 8; kc++) qf[kc] = *(const bf16x8*)(qrow + kc * 16);
  }

  f32x16 oacc[4];
#pragma unroll
  for (int i = 0; i < 4; i++) oacc[i] = (f32x16)(0.f);
  float lsum = 0.f;

  // ---------- phase 1 ----------
  stageK(0, 0); stageV(0, 0);
  for (int t = 0; t < nt; t++) {
    const int b = t & 1;
    const int kb = t * 64;
    if (t + 1 < nt) { stageK(b ^ 1, t + 1); stageV(b ^ 1, t + 1); WAITVM8(); }
    else            { WAITVM0(); }
    __builtin_amdgcn_s_barrier();

    if (kb <= qmaxw) {
      // QK^T swapped: C[permkey][q]
      f32x16 sf[2];
      sf[0] = (f32x16)(0.f); sf[1] = (f32x16)(0.f);
      __builtin_amdgcn_s_setprio(1);
#pragma unroll
      for (int kc = 0; kc < 8; kc++)
#pragma unroll
        for (int bl = 0; bl < 2; bl++) {
          int x = bl * 32 + l31;
          bf16x8 kf = *(const bf16x8*)(&Ks[b][x * 128 + (((kc * 2 + h2) ^ (lane & 7)) << 3)]);
          sf[bl] = __builtin_amdgcn_mfma_f32_32x32x16_bf16(kf, qf[kc], sf[bl], 0, 0, 0);
        }
      __builtin_amdgcn_s_setprio(0);

      // softmax (fixed basis 0); real key of sf[bl][4a+c] =
      // kb + bl*32 + (a>>1)*16 + h2*8 + (a&1)*4 + c
      float p[2][16];
      const bool diag = (kb + 63 > qbase);
#pragma unroll
      for (int bl = 0; bl < 2; bl++)
#pragma unroll
        for (int a = 0; a < 4; a++)
#pragma unroll
          for (int cc = 0; cc < 4; cc++) {
            float pv = exp2f(sf[bl][a * 4 + cc] * CS);
            if (diag) {
              int key = kb + bl * 32 + (a >> 1) * 16 + h2 * 8 + (a & 1) * 4 + cc;
              if (key > qglob) pv = 0.f;
            }
            p[bl][a * 4 + cc] = pv;
            lsum += pv;
          }

      // pack PV A-frags: pa[s] elem j = p[s>>1][8*(s&1) + j]
      bf16x8 pa[4];
#pragma unroll
      for (int s = 0; s < 4; s++) {
        const int bl = s >> 1, base = 8 * (s & 1);
        u32x4 pw;
        pw[0] = cvt_pk_bf16(p[bl][base + 0], p[bl][base + 1]);
        pw[1] = cvt_pk_bf16(p[bl][base + 2], p[bl][base + 3]);
        pw[2] = cvt_pk_bf16(p[bl][base + 4], p[bl][base + 5]);
        pw[3] = cvt_pk_bf16(p[bl][base + 6], p[bl][base + 7]);
        pa[s] = __builtin_bit_cast(bf16x8, pw);
      }

      // PV: C[q][d]
      __builtin_amdgcn_s_setprio(1);
#pragma unroll
      for (int s = 0; s < 4; s++)
#pragma unroll
        for (int db = 0; db < 4; db++) {
          int d = db * 32 + l31;
          bf16x8 vf = *(const bf16x8*)(&Vs[b][d * 64 + (((s * 2 + h2) ^ (lane & 7)) << 3)]);
          oacc[db] = __builtin_amdgcn_mfma_f32_32x32x16_bf16(pa[s], vf, oacc[db], 0, 0, 0);
        }
      __builtin_amdgcn_s_setprio(0);
    }
    __builtin_amdgcn_s_barrier();
  }

  // l reduce (halves) -> per-reg reciprocal table
  lsum += __shfl_xor(lsum, 32);
  float rlv = 1.f / lsum;           // valid for q-row = l31
  float rl16[16];
#pragma unroll
  for (int r = 0; r < 16; r++)
    rl16[r] = __shfl(rlv, (r & 3) + 8 * (r >> 2) + 4 * h2);

  // write O: lane holds d-col = db*32 + l31, q-rows by reg
#pragma unroll
  for (int db = 0; db < 4; db++) {
    int d = db * 32 + l31;
#pragma unroll
    for (int r = 0; r < 16; r++) {
      int qq = qbase + (r & 3) + 8 * (r >> 2) + 4 * h2;
      attn_out[(size_t)qq * HID_DIM + h * HD + d] = f2bf(oacc[db][r] * rl16[r]);
    }
  }

  // ---------- phase 2: normalized prob column sums ----------
  const int xl = (l31 & 0x13) | ((l31 & 4) << 1) | ((l31 & 8) >> 1);  // perm5
  stageK(0, 0);
  for (int t = 0; t < nt; t++) {
    const int b = t & 1;
    const int kb = t * 64;
    if (t + 1 < nt) { stageK(b ^ 1, t + 1); WAITVM4(); }
    else            { WAITVM0(); }
    __builtin_amdgcn_s_barrier();

    if (kb <= qmaxw) {
      // unswapped: C[q][key], key-col = bl*32 + l31 via LDS row bl*32 + xl
      f32x16 sg[2];
      sg[0] = (f32x16)(0.f); sg[1] = (f32x16)(0.f);
      __builtin_amdgcn_s_setprio(1);
#pragma unroll
      for (int kc = 0; kc < 8; kc++)
#pragma unroll
        for (int bl = 0; bl < 2; bl++) {
          int x = bl * 32 + xl;
          bf16x8 kf = *(const bf16x8*)(&Ks[b][x * 128 + (((kc * 2 + h2) ^ (x & 7)) << 3)]);
          sg[bl] = __builtin_amdgcn_mfma_f32_32x32x16_bf16(qf[kc], kf, sg[bl], 0, 0, 0);
        }
      __builtin_amdgcn_s_setprio(0);

      const bool diag = (kb + 63 > qbase);
#pragma unroll
      for (int bl = 0; bl < 2; bl++) {
        int key = kb + bl * 32 + l31;
        float sum = 0.f;
#pragma unroll
        for (int r = 0; r < 16; r++) {
          float pv = exp2f(sg[bl][r] * CS) * rl16[r];
          if (diag && key > qbase + (r & 3) + 8 * (r >> 2) + 4 * h2) pv = 0.f;
          sum += pv;
        }
        sum += __shfl_xor(sum, 32);
        if (lane < 32) atomicAdd(&cs[key], sum);
      }
    }
    __builtin_amdgcn_s_barrier();
  }

  // flush colsums
  asm volatile("s_waitcnt lgkmcnt(0)" ::: "memory");
  __builtin_amdgcn_s_barrier();
  const int nk = nt * 64;
  for (int i = tid; i < nk; i += 256)
    atomicAdd(scores + (size_t)kvh * S_LEN + i, cs[i]);
}

// ---------------- launch ----------------
extern "C" void kernel_launch(void* const* d_in, const int* in_sizes, int n_in,
                              void* d_out, int out_size, void* d_ws, size_t ws_size,
                              hipStream_t stream) {
  const float* hs = (const float*)d_in[0];
  const float* wq = (const float*)d_in[1];
  const float* wk = (const float*)d_in[2];
  const float* wv = (const float*)d_in[3];
  const float* wo = (const float*)d_in[4];
  const int* pos = (const int*)d_in[5];
  float* out = (float*)d_out;

  char* ws = (char*)d_ws;
  const size_t off_hs   = 0;
  const size_t off_wqT  = off_hs   + (size_t)S_LEN * HID_DIM * 2;
  const size_t off_wkT  = off_wqT  + (size_t)HID_DIM * HID_DIM * 2;
  const size_t off_wvT  = off_wkT  + (size_t)1024 * HID_DIM * 2;
  const size_t off_woT  = off_wvT  + (size_t)1024 * HID_DIM * 2;
  const size_t off_Qr   = off_woT  + (size_t)HID_DIM * HID_DIM * 2;
  const size_t off_Kr   = off_Qr   + (size_t)NH * S_LEN * HD * 2;
  const size_t off_Vt   = off_Kr   + (size_t)NKV * S_LEN * HD * 2;
  const size_t off_attn = off_Vt   + (size_t)NKV * HD * S_LEN * 2;

  short* hsb  = (short*)(ws + off_hs);
  short* wqT  = (short*)(ws + off_wqT);
  short* wkT  = (short*)(ws + off_wkT);
  short* wvT  = (short*)(ws + off_wvT);
  short* woT  = (short*)(ws + off_woT);
  short* Qr   = (short*)(ws + off_Qr);
  short* Kr   = (short*)(ws + off_Kr);
  short* Vt   = (short*)(ws + off_Vt);
  short* attb = (short*)(ws + off_attn);

  cvt_kernel<<<dim3((S_LEN * HID_DIM) / 1024), 256, 0, stream>>>(hs, hsb, S_LEN * HID_DIM);
  tconv_kernel<<<dim3(128, 128), 256, 0, stream>>>(wq, wqT, HID_DIM, HID_DIM);
  tconv_kernel<<<dim3(32, 128), 256, 0, stream>>>(wk, wkT, HID_DIM, 1024);
  tconv_kernel<<<dim3(32, 128), 256, 0, stream>>>(wv, wvT, HID_DIM, 1024);
  tconv_kernel<<<dim3(128, 128), 256, 0, stream>>>(wo, woT, HID_DIM, HID_DIM);

  gemm_bt_kernel<3><<<768, 256, 0, stream>>>(hsb, wqT, Qr, S_LEN, 6144, HID_DIM, 8, 12);

  rope_kernel<<<dim3(S_LEN, 10), dim3(64, 4), 0, stream>>>(Qr, Kr, pos);

  hipMemsetAsync(out + (size_t)S_LEN * HID_DIM, 0, (size_t)NKV * S_LEN * sizeof(float), stream);
  attn_kernel<<<512, 256, 0, stream>>>(Qr, Kr, Vt, attb, out + (size_t)S_LEN * HID_DIM);

  gemm_bt_kernel<2><<<512, 256, 0, stream>>>(attb, woT, out, S_LEN, HID_DIM, HID_DIM, 8, 8);
}

// Round 9
// 400.495 us; speedup vs baseline: 1.0124x; 1.0030x over previous
//
#include <hip/hip_runtime.h>
#include <hip/hip_bf16.h>
#include <cstdint>
#include <cstddef>

#define S_LEN 2048
#define HID_DIM 4096
#define NH 32
#define NKV 8
#define HD 128
#define LOG2E 1.4426950408889634f
#define SCALE 0.08838834764831845f

typedef __attribute__((ext_vector_type(8))) short bf16x8;
typedef __attribute__((ext_vector_type(4))) float f32x4;
typedef __attribute__((ext_vector_type(16))) float f32x16;
typedef __attribute__((ext_vector_type(4))) short short4v;
typedef __attribute__((ext_vector_type(4))) unsigned u32x4;

__device__ __forceinline__ short f2bf(float f) {
  union { float f; unsigned u; } v; v.f = f;
  return (short)((v.u + 0x7fffu + ((v.u >> 16) & 1u)) >> 16);
}
__device__ __forceinline__ float bf2f(short s) {
  union { unsigned u; float f; } v; v.u = ((unsigned)(unsigned short)s) << 16;
  return v.f;
}
__device__ __forceinline__ unsigned cvt_pk_bf16(float lo, float hi) {
  unsigned r;
  asm("v_cvt_pk_bf16_f32 %0, %1, %2" : "=v"(r) : "v"(lo), "v"(hi));
  return r;
}
__device__ __forceinline__ void gld_lds16(const void* g, void* l) {
  __builtin_amdgcn_global_load_lds((const __attribute__((address_space(1))) unsigned*)g,
                                   (__attribute__((address_space(3))) unsigned*)l, 16, 0, 0);
}

#define WAITVM4() asm volatile("s_waitcnt vmcnt(4)" ::: "memory")
#define WAITVM2() asm volatile("s_waitcnt vmcnt(2)" ::: "memory")
#define WAITVM0() asm volatile("s_waitcnt vmcnt(0)" ::: "memory")

// ---------------- fp32 -> bf16 elementwise ----------------
__global__ void cvt_kernel(const float* __restrict__ in, short* __restrict__ out, int n) {
  int i = (blockIdx.x * 256 + threadIdx.x) * 4;
  if (i < n) {
    float4 f = *(const float4*)(in + i);
    short4v o = { f2bf(f.x), f2bf(f.y), f2bf(f.z), f2bf(f.w) };
    *(short4v*)(out + i) = o;
  }
}

// ---------------- fp32 [R][C] -> bf16 [C][R] transpose-convert ----------------
__global__ void tconv_kernel(const float* __restrict__ in, short* __restrict__ out, int R, int C) {
  __shared__ float tile[32][33];
  int tr = blockIdx.y * 32, tc = blockIdx.x * 32;
  int tx = threadIdx.x & 31, ty = threadIdx.x >> 5; // ty 0..7
#pragma unroll
  for (int i = 0; i < 32; i += 8)
    tile[ty + i][tx] = in[(size_t)(tr + ty + i) * C + tc + tx];
  __syncthreads();
#pragma unroll
  for (int i = 0; i < 32; i += 8)
    out[(size_t)(tc + ty + i) * R + tr + tx] = f2bf(tile[tx][ty + i]);
}

// ---------------- GEMM: C[M][N] = A[M][K] * Bt[N][K]^T ----------------
// Double-buffered LDS, counted vmcnt, 4 blocks/CU, per-XCD squarish regions.
// MODE 2: write fp32 out[m][n]
// MODE 3: fused QKV epilogue.
template<int MODE>
__global__ __launch_bounds__(256, 4) void gemm_bt_kernel(
    const short* __restrict__ A, const short* __restrict__ Bt,
    void* __restrict__ Cout, int M, int N, int K, int rchunk, int cchunk)
{
  __shared__ short As[2][128 * 32];
  __shared__ short Bs[2][128 * 32];
  const int tid = threadIdx.x;
  const int lane = tid & 63;
  const int w = tid >> 6;
  const int wm = w >> 1, wn = w & 1;
  const int xcd = blockIdx.x & 7;
  const int local = blockIdx.x >> 3;
  const int by = (xcd >> 2) * rchunk + (local % rchunk);
  const int bx = (xcd & 3) * cchunk + (local / rchunk);
  const int m0 = by * 128, n0 = bx * 128;

  auto stage = [&](int bb, int k0) {
#pragma unroll
    for (int rep = 0; rep < 2; rep++) {
      int c = rep * 256 + tid;
      int row = c >> 2, slot = c & 3;
      int gs = slot ^ (row & 3);
      gld_lds16(A + (size_t)(m0 + row) * K + k0 + gs * 8, &As[bb][c * 8]);
      gld_lds16(Bt + (size_t)(n0 + row) * K + k0 + gs * 8, &Bs[bb][c * 8]);
    }
  };

  f32x4 acc[4][4];
#pragma unroll
  for (int i = 0; i < 4; i++)
#pragma unroll
    for (int j = 0; j < 4; j++) acc[i][j] = (f32x4){0.f, 0.f, 0.f, 0.f};

  const int NT = K >> 5;
  stage(0, 0);
  for (int kt = 0; kt < NT; kt++) {
    const int b = kt & 1;
    if (kt + 1 < NT) { stage(b ^ 1, (kt + 1) << 5); WAITVM4(); }
    else             { WAITVM0(); }
    __builtin_amdgcn_s_barrier();

    bf16x8 af[4], bf[4];
#pragma unroll
    for (int ms = 0; ms < 4; ms++) {
      int row = wm * 64 + ms * 16 + (lane & 15);
      af[ms] = *(const bf16x8*)(&As[b][row * 32 + (((lane >> 4) ^ (row & 3)) << 3)]);
    }
#pragma unroll
    for (int ns = 0; ns < 4; ns++) {
      int row = wn * 64 + ns * 16 + (lane & 15);
      bf[ns] = *(const bf16x8*)(&Bs[b][row * 32 + (((lane >> 4) ^ (row & 3)) << 3)]);
    }
#pragma unroll
    for (int ms = 0; ms < 4; ms++)
#pragma unroll
      for (int ns = 0; ns < 4; ns++)
        acc[ms][ns] = __builtin_amdgcn_mfma_f32_16x16x32_bf16(af[ms], bf[ns], acc[ms][ns], 0, 0, 0);

    __builtin_amdgcn_s_barrier();
  }

#pragma unroll
  for (int ms = 0; ms < 4; ms++) {
    int mb = m0 + wm * 64 + ms * 16 + ((lane >> 4) << 2);
#pragma unroll
    for (int ns = 0; ns < 4; ns++) {
      int n = n0 + wn * 64 + ns * 16 + (lane & 15);
      if (MODE == 3) {
        short* o = (short*)Cout;
        if (n < NH * HD) {
          int head = n >> 7, d = n & 127;
#pragma unroll
          for (int r = 0; r < 4; r++)
            o[((size_t)head * M + (mb + r)) * HD + d] = f2bf(acc[ms][ns][r]);
        } else if (n < (NH + NKV) * HD) {
          int head = (n - NH * HD) >> 7, d = n & 127;
          short* ok = o + (size_t)NH * S_LEN * HD;
#pragma unroll
          for (int r = 0; r < 4; r++)
            ok[((size_t)head * M + (mb + r)) * HD + d] = f2bf(acc[ms][ns][r]);
        } else {
          int head = (n - (NH + NKV) * HD) >> 7, d = n & 127;
          short* ov = o + (size_t)(NH + NKV) * S_LEN * HD;
          short4v pk;
#pragma unroll
          for (int r = 0; r < 4; r++) pk[r] = f2bf(acc[ms][ns][r]);
          *(short4v*)(ov + ((size_t)head * HD + d) * M + mb) = pk;
        }
      } else {
        float* o = (float*)Cout;
#pragma unroll
        for (int r = 0; r < 4; r++)
          o[(size_t)(mb + r) * N + n] = acc[ms][ns][r];
      }
    }
  }
}

// ---------------- RoPE in-place on Q [NH][S][HD] and K [NKV][S][HD] (bf16) ----------------
__global__ void rope_kernel(short* __restrict__ q, short* __restrict__ k,
                            const int* __restrict__ pos_ids) {
  const int s = blockIdx.x;
  const int hh = blockIdx.y * 4 + threadIdx.y;  // 0..39
  const int d = threadIdx.x;                    // 0..63
  const float pos = (float)pos_ids[s];
  const float inv = __expf(-(float)d * 0.14391157f); // ln(10000)/64
  float sn, c;
  __sincosf(pos * inv, &sn, &c);
  short* base = (hh < NH) ? (q + ((size_t)hh * S_LEN + s) * HD)
                          : (k + ((size_t)(hh - NH) * S_LEN + s) * HD);
  float x1 = bf2f(base[d]), x2 = bf2f(base[d + 64]);
  base[d] = f2bf(x1 * c - x2 * sn);
  base[d + 64] = f2bf(x2 * c + x1 * sn);
}

// ---------------- flash attention + eviction scores (32x32x16 MFMA) ----------------
// 256 blocks x 512 threads (8 waves x 32 q-rows). Waves 0-3 work strip qt=pr,
// waves 4-7 strip 15-pr CONCURRENTLY, sharing each staged K/V tile -> block
// work is near-uniform (ntmax = 32-2pr tiles), heavy-first. kvh == XCD.
// K stored with key bits 2<->3 swapped: swapped QK^T (C[key][q]) output is
// exactly lane-local for the PV A-fragment. Double-buffered staging with
// counted vmcnt. Fixed softmax basis m==0; per-thread l partial, one reduce.
__global__ __launch_bounds__(512, 2) void attn_kernel(
    const short* __restrict__ Qr, const short* __restrict__ Kr, const short* __restrict__ Vt,
    short* __restrict__ attn_out, float* __restrict__ scores)
{
  __shared__ short Ks[2][64 * 128];  // [permrow][hd], 16B slots XOR-swizzled by (row&7)
  __shared__ short Vs[2][128 * 64];  // [d][key],     16B slots XOR-swizzled by (d&7)
  __shared__ float cs[2048];

  const int tid = threadIdx.x;
  const int lane = tid & 63;
  const int w = tid >> 6;        // 0..7
  const int h2 = lane >> 5;      // k-half
  const int l31 = lane & 31;
  const int xcd = blockIdx.x & 7;
  const int j = blockIdx.x >> 3; // 0..31
  const int pr = j >> 2;         // 0..7  (ascending -> heavy ntmax first)
  const int h = xcd * 4 + (j & 3);
  const int kvh = xcd;
  const int qt = (w < 4) ? pr : (15 - pr);
  const int w4 = w & 3;
  const float CS = SCALE * LOG2E;

  const short* KrB = Kr + (size_t)kvh * S_LEN * HD;
  const short* VtB = Vt + (size_t)kvh * HD * S_LEN;

  for (int i = tid; i < 2048; i += 512) cs[i] = 0.f;

  auto stageK = [&](int bb, int t) {
    const int kb2 = t * 64;
#pragma unroll
    for (int rep = 0; rep < 2; rep++) {
      int c = rep * 512 + tid;
      int x = c >> 4, slot = c & 15;
      int key = (x & 0x33) | ((x & 4) << 1) | ((x & 8) >> 1);  // swap bits 2,3
      int gs = slot ^ (x & 7);
      gld_lds16(KrB + (size_t)(kb2 + key) * HD + gs * 8, &Ks[bb][c * 8]);
    }
  };
  auto stageV = [&](int bb, int t) {
    const int kb2 = t * 64;
#pragma unroll
    for (int rep = 0; rep < 2; rep++) {
      int c = rep * 512 + tid;
      int d = c >> 3, slot = c & 7;
      int gs = slot ^ (d & 7);
      gld_lds16(VtB + (size_t)d * S_LEN + kb2 + gs * 8, &Vs[bb][c * 8]);
    }
  };

  const int ntmax = 2 * (15 - pr) + 2;
  const int qbase = qt * 128 + w4 * 32;
  const int qglob = qbase + l31;
  const int qmaxw = qbase + 31;

  // Q fragments: q = qglob, hd = kc*16 + h2*8 + j
  bf16x8 qf[8];
  {
    const short* qrow = Qr + ((size_t)h * S_LEN + qglob) * HD + h2 * 8;
#pragma unroll
    for (int kc = 0; kc < 8; kc++) qf[kc] = *(const bf16x8*)(qrow + kc * 16);
  }

  f32x16 oacc[4];
#pragma unroll
  for (int i = 0; i < 4; i++) oacc[i] = (f32x16)(0.f);
  float lsum = 0.f;

  // ---------- phase 1 ----------
  stageK(0, 0); stageV(0, 0);
  for (int t = 0; t < ntmax; t++) {
    const int b = t & 1;
    const int kb = t * 64;
    if (t + 1 < ntmax) { stageK(b ^ 1, t + 1); stageV(b ^ 1, t + 1); WAITVM4(); }
    else               { WAITVM0(); }
    __builtin_amdgcn_s_barrier();

    if (kb <= qmaxw) {
      // QK^T swapped: C[permkey][q]
      f32x16 sf[2];
      sf[0] = (f32x16)(0.f); sf[1] = (f32x16)(0.f);
      __builtin_amdgcn_s_setprio(1);
#pragma unroll
      for (int kc = 0; kc < 8; kc++)
#pragma unroll
        for (int bl = 0; bl < 2; bl++) {
          int x = bl * 32 + l31;
          bf16x8 kf = *(const bf16x8*)(&Ks[b][x * 128 + (((kc * 2 + h2) ^ (lane & 7)) << 3)]);
          sf[bl] = __builtin_amdgcn_mfma_f32_32x32x16_bf16(kf, qf[kc], sf[bl], 0, 0, 0);
        }
      __builtin_amdgcn_s_setprio(0);

      // softmax (fixed basis 0); real key of sf[bl][4a+c] =
      // kb + bl*32 + (a>>1)*16 + h2*8 + (a&1)*4 + c
      float p[2][16];
      const bool diag = (kb + 63 > qbase);
#pragma unroll
      for (int bl = 0; bl < 2; bl++)
#pragma unroll
        for (int a = 0; a < 4; a++)
#pragma unroll
          for (int cc = 0; cc < 4; cc++) {
            float pv = exp2f(sf[bl][a * 4 + cc] * CS);
            if (diag) {
              int key = kb + bl * 32 + (a >> 1) * 16 + h2 * 8 + (a & 1) * 4 + cc;
              if (key > qglob) pv = 0.f;
            }
            p[bl][a * 4 + cc] = pv;
            lsum += pv;
          }

      // pack PV A-frags: pa[s] elem j = p[s>>1][8*(s&1) + j]
      bf16x8 pa[4];
#pragma unroll
      for (int s = 0; s < 4; s++) {
        const int bl = s >> 1, base = 8 * (s & 1);
        u32x4 pw;
        pw[0] = cvt_pk_bf16(p[bl][base + 0], p[bl][base + 1]);
        pw[1] = cvt_pk_bf16(p[bl][base + 2], p[bl][base + 3]);
        pw[2] = cvt_pk_bf16(p[bl][base + 4], p[bl][base + 5]);
        pw[3] = cvt_pk_bf16(p[bl][base + 6], p[bl][base + 7]);
        pa[s] = __builtin_bit_cast(bf16x8, pw);
      }

      // PV: C[q][d]
      __builtin_amdgcn_s_setprio(1);
#pragma unroll
      for (int s = 0; s < 4; s++)
#pragma unroll
        for (int db = 0; db < 4; db++) {
          int d = db * 32 + l31;
          bf16x8 vf = *(const bf16x8*)(&Vs[b][d * 64 + (((s * 2 + h2) ^ (lane & 7)) << 3)]);
          oacc[db] = __builtin_amdgcn_mfma_f32_32x32x16_bf16(pa[s], vf, oacc[db], 0, 0, 0);
        }
      __builtin_amdgcn_s_setprio(0);
    }
    __builtin_amdgcn_s_barrier();
  }

  // l reduce (halves) -> per-reg reciprocal table
  lsum += __shfl_xor(lsum, 32);
  float rlv = 1.f / lsum;           // valid for q-row = l31
  float rl16[16];
#pragma unroll
  for (int r = 0; r < 16; r++)
    rl16[r] = __shfl(rlv, (r & 3) + 8 * (r >> 2) + 4 * h2);

  // write O: lane holds d-col = db*32 + l31, q-rows by reg
#pragma unroll
  for (int db = 0; db < 4; db++) {
    int d = db * 32 + l31;
#pragma unroll
    for (int r = 0; r < 16; r++) {
      int qq = qbase + (r & 3) + 8 * (r >> 2) + 4 * h2;
      attn_out[(size_t)qq * HID_DIM + h * HD + d] = f2bf(oacc[db][r] * rl16[r]);
    }
  }

  // ---------- phase 2: normalized prob column sums ----------
  const int xl = (l31 & 0x13) | ((l31 & 4) << 1) | ((l31 & 8) >> 1);  // perm5
  stageK(0, 0);
  for (int t = 0; t < ntmax; t++) {
    const int b = t & 1;
    const int kb = t * 64;
    if (t + 1 < ntmax) { stageK(b ^ 1, t + 1); WAITVM2(); }
    else               { WAITVM0(); }
    __builtin_amdgcn_s_barrier();

    if (kb <= qmaxw) {
      // unswapped: C[q][key], key-col = bl*32 + l31 via LDS row bl*32 + xl
      f32x16 sg[2];
      sg[0] = (f32x16)(0.f); sg[1] = (f32x16)(0.f);
      __builtin_amdgcn_s_setprio(1);
#pragma unroll
      for (int kc = 0; kc < 8; kc++)
#pragma unroll
        for (int bl = 0; bl < 2; bl++) {
          int x = bl * 32 + xl;
          bf16x8 kf = *(const bf16x8*)(&Ks[b][x * 128 + (((kc * 2 + h2) ^ (x & 7)) << 3)]);
          sg[bl] = __builtin_amdgcn_mfma_f32_32x32x16_bf16(qf[kc], kf, sg[bl], 0, 0, 0);
        }
      __builtin_amdgcn_s_setprio(0);

      const bool diag = (kb + 63 > qbase);
#pragma unroll
      for (int bl = 0; bl < 2; bl++) {
        int key = kb + bl * 32 + l31;
        float sum = 0.f;
#pragma unroll
        for (int r = 0; r < 16; r++) {
          float pv = exp2f(sg[bl][r] * CS) * rl16[r];
          if (diag && key > qbase + (r & 3) + 8 * (r >> 2) + 4 * h2) pv = 0.f;
          sum += pv;
        }
        sum += __shfl_xor(sum, 32);
        if (lane < 32) atomicAdd(&cs[key], sum);
      }
    }
    __builtin_amdgcn_s_barrier();
  }

  // flush colsums
  asm volatile("s_waitcnt lgkmcnt(0)" ::: "memory");
  __builtin_amdgcn_s_barrier();
  const int nk = ntmax * 64;
  for (int i = tid; i < nk; i += 512)
    atomicAdd(scores + (size_t)kvh * S_LEN + i, cs[i]);
}

// ---------------- launch ----------------
extern "C" void kernel_launch(void* const* d_in, const int* in_sizes, int n_in,
                              void* d_out, int out_size, void* d_ws, size_t ws_size,
                              hipStream_t stream) {
  const float* hs = (const float*)d_in[0];
  const float* wq = (const float*)d_in[1];
  const float* wk = (const float*)d_in[2];
  const float* wv = (const float*)d_in[3];
  const float* wo = (const float*)d_in[4];
  const int* pos = (const int*)d_in[5];
  float* out = (float*)d_out;

  char* ws = (char*)d_ws;
  const size_t off_hs   = 0;
  const size_t off_wqT  = off_hs   + (size_t)S_LEN * HID_DIM * 2;
  const size_t off_wkT  = off_wqT  + (size_t)HID_DIM * HID_DIM * 2;
  const size_t off_wvT  = off_wkT  + (size_t)1024 * HID_DIM * 2;
  const size_t off_woT  = off_wvT  + (size_t)1024 * HID_DIM * 2;
  const size_t off_Qr   = off_woT  + (size_t)HID_DIM * HID_DIM * 2;
  const size_t off_Kr   = off_Qr   + (size_t)NH * S_LEN * HD * 2;
  const size_t off_Vt   = off_Kr   + (size_t)NKV * S_LEN * HD * 2;
  const size_t off_attn = off_Vt   + (size_t)NKV * HD * S_LEN * 2;

  short* hsb  = (short*)(ws + off_hs);
  short* wqT  = (short*)(ws + off_wqT);
  short* wkT  = (short*)(ws + off_wkT);
  short* wvT  = (short*)(ws + off_wvT);
  short* woT  = (short*)(ws + off_woT);
  short* Qr   = (short*)(ws + off_Qr);
  short* Kr   = (short*)(ws + off_Kr);
  short* Vt   = (short*)(ws + off_Vt);
  short* attb = (short*)(ws + off_attn);

  cvt_kernel<<<dim3((S_LEN * HID_DIM) / 1024), 256, 0, stream>>>(hs, hsb, S_LEN * HID_DIM);
  tconv_kernel<<<dim3(128, 128), 256, 0, stream>>>(wq, wqT, HID_DIM, HID_DIM);
  tconv_kernel<<<dim3(32, 128), 256, 0, stream>>>(wk, wkT, HID_DIM, 1024);
  tconv_kernel<<<dim3(32, 128), 256, 0, stream>>>(wv, wvT, HID_DIM, 1024);
  tconv_kernel<<<dim3(128, 128), 256, 0, stream>>>(wo, woT, HID_DIM, HID_DIM);

  gemm_bt_kernel<3><<<768, 256, 0, stream>>>(hsb, wqT, Qr, S_LEN, 6144, HID_DIM, 8, 12);

  rope_kernel<<<dim3(S_LEN, 10), dim3(64, 4), 0, stream>>>(Qr, Kr, pos);

  hipMemsetAsync(out + (size_t)S_LEN * HID_DIM, 0, (size_t)NKV * S_LEN * sizeof(float), stream);
  attn_kernel<<<256, 512, 0, stream>>>(Qr, Kr, Vt, attb, out + (size_t)S_LEN * HID_DIM);

  gemm_bt_kernel<2><<<512, 256, 0, stream>>>(attb, woT, out, S_LEN, HID_DIM, HID_DIM, 8, 8);
}

// Round 10
// 391.905 us; speedup vs baseline: 1.0346x; 1.0219x over previous
//
#include <hip/hip_runtime.h>
#include <hip/hip_bf16.h>
#include <cstdint>
#include <cstddef>

#define S_LEN 2048
#define HID_DIM 4096
#define NH 32
#define NKV 8
#define HD 128
#define LOG2E 1.4426950408889634f
#define SCALE 0.08838834764831845f

typedef __attribute__((ext_vector_type(8))) short bf16x8;
typedef __attribute__((ext_vector_type(4))) float f32x4;
typedef __attribute__((ext_vector_type(16))) float f32x16;
typedef __attribute__((ext_vector_type(4))) short short4v;
typedef __attribute__((ext_vector_type(4))) unsigned u32x4;

__device__ __forceinline__ short f2bf(float f) {
  union { float f; unsigned u; } v; v.f = f;
  return (short)((v.u + 0x7fffu + ((v.u >> 16) & 1u)) >> 16);
}
__device__ __forceinline__ float bf2f(short s) {
  union { unsigned u; float f; } v; v.u = ((unsigned)(unsigned short)s) << 16;
  return v.f;
}
__device__ __forceinline__ unsigned cvt_pk_bf16(float lo, float hi) {
  unsigned r;
  asm("v_cvt_pk_bf16_f32 %0, %1, %2" : "=v"(r) : "v"(lo), "v"(hi));
  return r;
}
__device__ __forceinline__ void gld_lds16(const void* g, void* l) {
  __builtin_amdgcn_global_load_lds((const __attribute__((address_space(1))) unsigned*)g,
                                   (__attribute__((address_space(3))) unsigned*)l, 16, 0, 0);
}

#define WAITVM8() asm volatile("s_waitcnt vmcnt(8)" ::: "memory")
#define WAITVM4() asm volatile("s_waitcnt vmcnt(4)" ::: "memory")
#define WAITVM0() asm volatile("s_waitcnt vmcnt(0)" ::: "memory")

// ---------------- fp32 -> bf16 elementwise ----------------
__global__ void cvt_kernel(const float* __restrict__ in, short* __restrict__ out, int n) {
  int i = (blockIdx.x * 256 + threadIdx.x) * 4;
  if (i < n) {
    float4 f = *(const float4*)(in + i);
    short4v o = { f2bf(f.x), f2bf(f.y), f2bf(f.z), f2bf(f.w) };
    *(short4v*)(out + i) = o;
  }
}

// ---------------- fp32 [R][C] -> bf16 [C][R] transpose-convert ----------------
__global__ void tconv_kernel(const float* __restrict__ in, short* __restrict__ out, int R, int C) {
  __shared__ float tile[32][33];
  int tr = blockIdx.y * 32, tc = blockIdx.x * 32;
  int tx = threadIdx.x & 31, ty = threadIdx.x >> 5; // ty 0..7
#pragma unroll
  for (int i = 0; i < 32; i += 8)
    tile[ty + i][tx] = in[(size_t)(tr + ty + i) * C + tc + tx];
  __syncthreads();
#pragma unroll
  for (int i = 0; i < 32; i += 8)
    out[(size_t)(tc + ty + i) * R + tr + tx] = f2bf(tile[tx][ty + i]);
}

// ---------------- GEMM: C[M][N] = A[M][K] * Bt[N][K]^T ----------------
// Double-buffered LDS, counted vmcnt, 4 blocks/CU, per-XCD squarish regions.
// MODE 2: write fp32 out[m][n]
// MODE 3: fused QKV epilogue.
template<int MODE>
__global__ __launch_bounds__(256, 4) void gemm_bt_kernel(
    const short* __restrict__ A, const short* __restrict__ Bt,
    void* __restrict__ Cout, int M, int N, int K, int rchunk, int cchunk)
{
  __shared__ short As[2][128 * 32];
  __shared__ short Bs[2][128 * 32];
  const int tid = threadIdx.x;
  const int lane = tid & 63;
  const int w = tid >> 6;
  const int wm = w >> 1, wn = w & 1;
  const int xcd = blockIdx.x & 7;
  const int local = blockIdx.x >> 3;
  const int by = (xcd >> 2) * rchunk + (local % rchunk);
  const int bx = (xcd & 3) * cchunk + (local / rchunk);
  const int m0 = by * 128, n0 = bx * 128;

  auto stage = [&](int bb, int k0) {
#pragma unroll
    for (int rep = 0; rep < 2; rep++) {
      int c = rep * 256 + tid;
      int row = c >> 2, slot = c & 3;
      int gs = slot ^ (row & 3);
      gld_lds16(A + (size_t)(m0 + row) * K + k0 + gs * 8, &As[bb][c * 8]);
      gld_lds16(Bt + (size_t)(n0 + row) * K + k0 + gs * 8, &Bs[bb][c * 8]);
    }
  };

  f32x4 acc[4][4];
#pragma unroll
  for (int i = 0; i < 4; i++)
#pragma unroll
    for (int j = 0; j < 4; j++) acc[i][j] = (f32x4){0.f, 0.f, 0.f, 0.f};

  const int NT = K >> 5;
  stage(0, 0);
  for (int kt = 0; kt < NT; kt++) {
    const int b = kt & 1;
    if (kt + 1 < NT) { stage(b ^ 1, (kt + 1) << 5); WAITVM4(); }
    else             { WAITVM0(); }
    __builtin_amdgcn_s_barrier();

    bf16x8 af[4], bf[4];
#pragma unroll
    for (int ms = 0; ms < 4; ms++) {
      int row = wm * 64 + ms * 16 + (lane & 15);
      af[ms] = *(const bf16x8*)(&As[b][row * 32 + (((lane >> 4) ^ (row & 3)) << 3)]);
    }
#pragma unroll
    for (int ns = 0; ns < 4; ns++) {
      int row = wn * 64 + ns * 16 + (lane & 15);
      bf[ns] = *(const bf16x8*)(&Bs[b][row * 32 + (((lane >> 4) ^ (row & 3)) << 3)]);
    }
#pragma unroll
    for (int ms = 0; ms < 4; ms++)
#pragma unroll
      for (int ns = 0; ns < 4; ns++)
        acc[ms][ns] = __builtin_amdgcn_mfma_f32_16x16x32_bf16(af[ms], bf[ns], acc[ms][ns], 0, 0, 0);

    __builtin_amdgcn_s_barrier();
  }

#pragma unroll
  for (int ms = 0; ms < 4; ms++) {
    int mb = m0 + wm * 64 + ms * 16 + ((lane >> 4) << 2);
#pragma unroll
    for (int ns = 0; ns < 4; ns++) {
      int n = n0 + wn * 64 + ns * 16 + (lane & 15);
      if (MODE == 3) {
        short* o = (short*)Cout;
        if (n < NH * HD) {
          int head = n >> 7, d = n & 127;
#pragma unroll
          for (int r = 0; r < 4; r++)
            o[((size_t)head * M + (mb + r)) * HD + d] = f2bf(acc[ms][ns][r]);
        } else if (n < (NH + NKV) * HD) {
          int head = (n - NH * HD) >> 7, d = n & 127;
          short* ok = o + (size_t)NH * S_LEN * HD;
#pragma unroll
          for (int r = 0; r < 4; r++)
            ok[((size_t)head * M + (mb + r)) * HD + d] = f2bf(acc[ms][ns][r]);
        } else {
          int head = (n - (NH + NKV) * HD) >> 7, d = n & 127;
          short* ov = o + (size_t)(NH + NKV) * S_LEN * HD;
          short4v pk;
#pragma unroll
          for (int r = 0; r < 4; r++) pk[r] = f2bf(acc[ms][ns][r]);
          *(short4v*)(ov + ((size_t)head * HD + d) * M + mb) = pk;
        }
      } else {
        float* o = (float*)Cout;
#pragma unroll
        for (int r = 0; r < 4; r++)
          o[(size_t)(mb + r) * N + n] = acc[ms][ns][r];
      }
    }
  }
}

// ---------------- RoPE in-place on Q [NH][S][HD] and K [NKV][S][HD] (bf16) ----------------
__global__ void rope_kernel(short* __restrict__ q, short* __restrict__ k,
                            const int* __restrict__ pos_ids) {
  const int s = blockIdx.x;
  const int hh = blockIdx.y * 4 + threadIdx.y;  // 0..39
  const int d = threadIdx.x;                    // 0..63
  const float pos = (float)pos_ids[s];
  const float inv = __expf(-(float)d * 0.14391157f); // ln(10000)/64
  float sn, c;
  __sincosf(pos * inv, &sn, &c);
  short* base = (hh < NH) ? (q + ((size_t)hh * S_LEN + s) * HD)
                          : (k + ((size_t)(hh - NH) * S_LEN + s) * HD);
  float x1 = bf2f(base[d]), x2 = bf2f(base[d + 64]);
  base[d] = f2bf(x1 * c - x2 * sn);
  base[d + 64] = f2bf(x2 * c + x1 * sn);
}

// ---------------- flash attention + eviction scores (32x32x16 MFMA) ----------------
// 512 blocks x 256 threads (4 waves). Block = (head, pair p): 64-row strips
// qt = 31-p then p SEQUENTIALLY -> exactly 33 staged tiles per block (uniform,
// any schedule is balanced; 2 blocks/CU overlap at barriers). kvh == XCD.
// Waves = (row-group r in {0,1}) x (key-half kh in {0,1}); each wave owns a
// 32q x 32k quadrant per tile; partial O/l combined via LDS once per strip.
// Phase 1: K LDS-staged with key bits 2<->3 swapped (QK^T C[key][q] output is
// lane-local for the PV A-frag); V LDS-staged. Counted-vmcnt double buffer.
// Phase 2 (colsums): BARRIER-FREE -- K fragments direct-loaded from L2 per
// lane (B-operand layout = plain rows), tiles split between kh waves.
// Fixed softmax basis m==0; l deferred.
__global__ __launch_bounds__(256, 2) void attn_kernel(
    const short* __restrict__ Qr, const short* __restrict__ Kr, const short* __restrict__ Vt,
    short* __restrict__ attn_out, float* __restrict__ scores)
{
  __shared__ short Ks[2][64 * 128];  // [permrow][hd], 16B slots XOR-swizzled by (row&7)
  __shared__ short Vs[2][128 * 64];  // [d][key],     16B slots XOR-swizzled by (d&7)
  __shared__ float cs[2048];

  const int tid = threadIdx.x;
  const int lane = tid & 63;
  const int w = tid >> 6;        // 0..3
  const int r = w & 1;           // row group
  const int kh = w >> 1;         // key half
  const int h2 = lane >> 5;
  const int l31 = lane & 31;
  const int xcd = blockIdx.x & 7;
  const int j = blockIdx.x >> 3; // 0..63
  const int h = xcd * 4 + (j & 3);
  const int p = j >> 2;          // pair 0..15
  const int kvh = xcd;
  const float CS = SCALE * LOG2E;

  const short* KrB = Kr + (size_t)kvh * S_LEN * HD;
  const short* VtB = Vt + (size_t)kvh * HD * S_LEN;

  for (int i = tid; i < 2048; i += 256) cs[i] = 0.f;

  float* obuf = (float*)Ks;          // 8192 floats = 32KB (after phase 1)
  float* lbuf = (float*)Vs;          // 64 floats
  float* rlbuf = lbuf + 64;          // 64 floats

  auto stageK = [&](int bb, int t) {
    const int kb2 = t * 64;
#pragma unroll
    for (int rep = 0; rep < 4; rep++) {
      int c = rep * 256 + tid;
      int x = c >> 4, slot = c & 15;
      int key = (x & 0x33) | ((x & 4) << 1) | ((x & 8) >> 1);  // swap bits 2,3
      int gs = slot ^ (x & 7);
      gld_lds16(KrB + (size_t)(kb2 + key) * HD + gs * 8, &Ks[bb][c * 8]);
    }
  };
  auto stageV = [&](int bb, int t) {
    const int kb2 = t * 64;
#pragma unroll
    for (int rep = 0; rep < 4; rep++) {
      int c = rep * 256 + tid;
      int d = c >> 3, slot = c & 7;
      int gs = slot ^ (d & 7);
      gld_lds16(VtB + (size_t)d * S_LEN + kb2 + gs * 8, &Vs[bb][c * 8]);
    }
  };

  for (int sidx = 0; sidx < 2; sidx++) {
    const int qt = sidx ? p : (31 - p);
    const int nt = qt + 1;
    const int qbase = qt * 64 + r * 32;
    const int qglob = qbase + l31;
    const int qmaxw = qbase + 31;

    // Q fragments: q = qglob, hd = kc*16 + h2*8 + e
    bf16x8 qf[8];
    {
      const short* qrow = Qr + ((size_t)h * S_LEN + qglob) * HD + h2 * 8;
#pragma unroll
      for (int kc = 0; kc < 8; kc++) qf[kc] = *(const bf16x8*)(qrow + kc * 16);
    }

    f32x16 oacc[4];
#pragma unroll
    for (int i = 0; i < 4; i++) oacc[i] = (f32x16)(0.f);
    float lsum = 0.f;

    // ---------- phase 1 (staged, double-buffered) ----------
    stageK(0, 0); stageV(0, 0);
    for (int t = 0; t < nt; t++) {
      const int b = t & 1;
      const int kb = t * 64;
      if (t + 1 < nt) { stageK(b ^ 1, t + 1); stageV(b ^ 1, t + 1); WAITVM8(); }
      else            { WAITVM0(); }
      __builtin_amdgcn_s_barrier();

      if (kb <= qmaxw) {
        // QK^T swapped: C[permkey][q], only this wave's key half kh
        f32x16 sf = (f32x16)(0.f);
        const int x = kh * 32 + l31;
        __builtin_amdgcn_s_setprio(1);
#pragma unroll
        for (int kc = 0; kc < 8; kc++) {
          bf16x8 kf = *(const bf16x8*)(&Ks[b][x * 128 + (((kc * 2 + h2) ^ (x & 7)) << 3)]);
          sf = __builtin_amdgcn_mfma_f32_32x32x16_bf16(kf, qf[kc], sf, 0, 0, 0);
        }
        __builtin_amdgcn_s_setprio(0);

        // softmax (fixed basis 0); key of sf[4a+cc] =
        // kb + kh*32 + (a>>1)*16 + h2*8 + (a&1)*4 + cc
        float pv16[16];
        const bool diag = (kb + 63 > qbase);
#pragma unroll
        for (int a = 0; a < 4; a++)
#pragma unroll
          for (int cc = 0; cc < 4; cc++) {
            float pv = exp2f(sf[a * 4 + cc] * CS);
            if (diag) {
              int key = kb + kh * 32 + (a >> 1) * 16 + h2 * 8 + (a & 1) * 4 + cc;
              if (key > qglob) pv = 0.f;
            }
            pv16[a * 4 + cc] = pv;
            lsum += pv;
          }

        // pack PV A-frags: pa[s'] elem e = pv16[8*s' + e]
        bf16x8 pa[2];
#pragma unroll
        for (int s = 0; s < 2; s++) {
          u32x4 pw;
          pw[0] = cvt_pk_bf16(pv16[8 * s + 0], pv16[8 * s + 1]);
          pw[1] = cvt_pk_bf16(pv16[8 * s + 2], pv16[8 * s + 3]);
          pw[2] = cvt_pk_bf16(pv16[8 * s + 4], pv16[8 * s + 5]);
          pw[3] = cvt_pk_bf16(pv16[8 * s + 6], pv16[8 * s + 7]);
          pa[s] = __builtin_bit_cast(bf16x8, pw);
        }

        // PV: C[q][d], partial over this key half
        __builtin_amdgcn_s_setprio(1);
#pragma unroll
        for (int s = 0; s < 2; s++) {
          const int g = kh * 2 + s;   // 16-wide key slice index
#pragma unroll
          for (int db = 0; db < 4; db++) {
            int d = db * 32 + l31;
            bf16x8 vf = *(const bf16x8*)(&Vs[b][d * 64 + (((g * 2 + h2) ^ (d & 7)) << 3)]);
            oacc[db] = __builtin_amdgcn_mfma_f32_32x32x16_bf16(pa[s], vf, oacc[db], 0, 0, 0);
          }
        }
        __builtin_amdgcn_s_setprio(0);
      }
      __builtin_amdgcn_s_barrier();
    }

    // ---------- O / l combine across key-halves ----------
    lsum += __shfl_xor(lsum, 32);    // combine h2 halves (same q, different keys)
    if (kh == 0) {
#pragma unroll
      for (int db = 0; db < 4; db++)
#pragma unroll
        for (int r16 = 0; r16 < 16; r16++) {
          int crow = (r16 & 3) + 8 * (r16 >> 2) + 4 * h2;
          obuf[(r * 32 + crow) * 128 + db * 32 + l31] = oacc[db][r16];
        }
      if (lane < 32) lbuf[r * 32 + l31] = lsum;
    }
    __builtin_amdgcn_s_barrier();

    if (kh == 1) {
      float ltot = lsum + lbuf[r * 32 + l31];
      float rlv = 1.f / ltot;
      float rl16[16];
#pragma unroll
      for (int r16 = 0; r16 < 16; r16++)
        rl16[r16] = __shfl(rlv, (r16 & 3) + 8 * (r16 >> 2) + 4 * h2);
#pragma unroll
      for (int db = 0; db < 4; db++) {
        int d = db * 32 + l31;
#pragma unroll
        for (int r16 = 0; r16 < 16; r16++) {
          int crow = (r16 & 3) + 8 * (r16 >> 2) + 4 * h2;
          float o = oacc[db][r16] + obuf[(r * 32 + crow) * 128 + d];
          attn_out[(size_t)(qbase + crow) * HID_DIM + h * HD + d] = f2bf(o * rl16[r16]);
        }
      }
      if (lane < 32) rlbuf[r * 32 + l31] = rlv;
    }
    __builtin_amdgcn_s_barrier();

    // all waves pick up per-row reciprocals for phase 2
    float rlv = rlbuf[r * 32 + l31];
    float rl16[16];
#pragma unroll
    for (int r16 = 0; r16 < 16; r16++)
      rl16[r16] = __shfl(rlv, (r16 & 3) + 8 * (r16 >> 2) + 4 * h2);
    __builtin_amdgcn_s_barrier();   // rlbuf read done before next strip's staging

    // ---------- phase 2: colsums, direct from L2, barrier-free ----------
    const int ntw = qmaxw / 64 + 1;
    for (int t = kh; t < ntw; t += 2) {
      const int kb = t * 64;
      f32x16 sg[2];
      sg[0] = (f32x16)(0.f); sg[1] = (f32x16)(0.f);
      __builtin_amdgcn_s_setprio(1);
#pragma unroll
      for (int kc = 0; kc < 8; kc++)
#pragma unroll
        for (int bl = 0; bl < 2; bl++) {
          bf16x8 kf = *(const bf16x8*)(KrB + (size_t)(kb + bl * 32 + l31) * HD + kc * 16 + h2 * 8);
          sg[bl] = __builtin_amdgcn_mfma_f32_32x32x16_bf16(qf[kc], kf, sg[bl], 0, 0, 0);
        }
      __builtin_amdgcn_s_setprio(0);

      const bool diag = (kb + 63 > qbase);
#pragma unroll
      for (int bl = 0; bl < 2; bl++) {
        int key = kb + bl * 32 + l31;
        float sum = 0.f;
#pragma unroll
        for (int r16 = 0; r16 < 16; r16++) {
          float pv = exp2f(sg[bl][r16] * CS) * rl16[r16];
          if (diag && key > qbase + (r16 & 3) + 8 * (r16 >> 2) + 4 * h2) pv = 0.f;
          sum += pv;
        }
        sum += __shfl_xor(sum, 32);
        if (lane < 32) atomicAdd(&cs[key], sum);
      }
    }
  }

  // flush colsums
  asm volatile("s_waitcnt lgkmcnt(0)" ::: "memory");
  __builtin_amdgcn_s_barrier();
  const int nk = (32 - p) * 64;
  for (int i = tid; i < nk; i += 256)
    atomicAdd(scores + (size_t)kvh * S_LEN + i, cs[i]);
}

// ---------------- launch ----------------
extern "C" void kernel_launch(void* const* d_in, const int* in_sizes, int n_in,
                              void* d_out, int out_size, void* d_ws, size_t ws_size,
                              hipStream_t stream) {
  const float* hs = (const float*)d_in[0];
  const float* wq = (const float*)d_in[1];
  const float* wk = (const float*)d_in[2];
  const float* wv = (const float*)d_in[3];
  const float* wo = (const float*)d_in[4];
  const int* pos = (const int*)d_in[5];
  float* out = (float*)d_out;

  char* ws = (char*)d_ws;
  const size_t off_hs   = 0;
  const size_t off_wqT  = off_hs   + (size_t)S_LEN * HID_DIM * 2;
  const size_t off_wkT  = off_wqT  + (size_t)HID_DIM * HID_DIM * 2;
  const size_t off_wvT  = off_wkT  + (size_t)1024 * HID_DIM * 2;
  const size_t off_woT  = off_wvT  + (size_t)1024 * HID_DIM * 2;
  const size_t off_Qr   = off_woT  + (size_t)HID_DIM * HID_DIM * 2;
  const size_t off_Kr   = off_Qr   + (size_t)NH * S_LEN * HD * 2;
  const size_t off_Vt   = off_Kr   + (size_t)NKV * S_LEN * HD * 2;
  const size_t off_attn = off_Vt   + (size_t)NKV * HD * S_LEN * 2;

  short* hsb  = (short*)(ws + off_hs);
  short* wqT  = (short*)(ws + off_wqT);
  short* wkT  = (short*)(ws + off_wkT);
  short* wvT  = (short*)(ws + off_wvT);
  short* woT  = (short*)(ws + off_woT);
  short* Qr   = (short*)(ws + off_Qr);
  short* Kr   = (short*)(ws + off_Kr);
  short* Vt   = (short*)(ws + off_Vt);
  short* attb = (short*)(ws + off_attn);

  cvt_kernel<<<dim3((S_LEN * HID_DIM) / 1024), 256, 0, stream>>>(hs, hsb, S_LEN * HID_DIM);
  tconv_kernel<<<dim3(128, 128), 256, 0, stream>>>(wq, wqT, HID_DIM, HID_DIM);
  tconv_kernel<<<dim3(32, 128), 256, 0, stream>>>(wk, wkT, HID_DIM, 1024);
  tconv_kernel<<<dim3(32, 128), 256, 0, stream>>>(wv, wvT, HID_DIM, 1024);
  tconv_kernel<<<dim3(128, 128), 256, 0, stream>>>(wo, woT, HID_DIM, HID_DIM);

  gemm_bt_kernel<3><<<768, 256, 0, stream>>>(hsb, wqT, Qr, S_LEN, 6144, HID_DIM, 8, 12);

  rope_kernel<<<dim3(S_LEN, 10), dim3(64, 4), 0, stream>>>(Qr, Kr, pos);

  hipMemsetAsync(out + (size_t)S_LEN * HID_DIM, 0, (size_t)NKV * S_LEN * sizeof(float), stream);
  attn_kernel<<<512, 256, 0, stream>>>(Qr, Kr, Vt, attb, out + (size_t)S_LEN * HID_DIM);

  gemm_bt_kernel<2><<<512, 256, 0, stream>>>(attb, woT, out, S_LEN, HID_DIM, HID_DIM, 8, 8);
}